// Round 1
// baseline (553.219 us; speedup 1.0000x reference)
//
#include <hip/hip_runtime.h>
#include <hip/hip_bf16.h>

// ---------------------------------------------------------------------------
// Lfm2ShortConv decode step:
//   proj = hs @ w_in.T ; B,C,x = split(proj)
//   Bx = B*x ; conv_out = sum_k [state | Bx] * conv_w ; y = (C*conv_out) @ w_out.T
//   new_state = scatter(state, idx, [state[...,1:], Bx])
// Strategy: bf16 MFMA for both GEMMs (threshold admits it), f32 elsewhere.
// ---------------------------------------------------------------------------

typedef __bf16 bf16x8 __attribute__((ext_vector_type(8)));
typedef float f32x4 __attribute__((ext_vector_type(4)));

__device__ __forceinline__ unsigned short f2bf(float f) {
    union { float f; unsigned int u; } c; c.f = f;
    unsigned int u = c.u;
    u = u + 0x7FFFu + ((u >> 16) & 1u);   // RNE
    return (unsigned short)(u >> 16);
}

// -------------------- f32 -> bf16 conversion (vectorized) ------------------
__global__ void cvt_f32_bf16(const float4* __restrict__ src,
                             ushort4* __restrict__ dst, int n4) {
    int i = blockIdx.x * blockDim.x + threadIdx.x;
    if (i >= n4) return;
    float4 v = src[i];
    ushort4 o;
    o.x = f2bf(v.x); o.y = f2bf(v.y); o.z = f2bf(v.z); o.w = f2bf(v.w);
    dst[i] = o;
}

// -------------------- bf16 GEMM: C[M,N] = A[M,K] * B[N,K]^T ----------------
// 128x128 tile, BK=32, 4 waves, each wave does 4x4 16x16x32 MFMA tiles.
// Staging via global_load_lds width=16 (wave-uniform base + lane*16).
// Requires M,N,K multiples of 128/128/32 (true here: 2048/6144/2048).

#define GTILE 128
#define GBK 32

__device__ __forceinline__ void gl_lds16(const unsigned short* g, unsigned short* l) {
    __builtin_amdgcn_global_load_lds(
        (const __attribute__((address_space(1))) unsigned int*)g,
        (__attribute__((address_space(3))) unsigned int*)l,
        16, 0, 0);
}

__global__ __launch_bounds__(256) void gemm_bt(
    const unsigned short* __restrict__ A,  // [M,K] bf16 bits
    const unsigned short* __restrict__ B,  // [N,K] bf16 bits
    float* __restrict__ C,                 // [M,N] f32
    int M, int N, int K)
{
    __shared__ __align__(16) unsigned short Asm[GTILE * GBK];
    __shared__ __align__(16) unsigned short Bsm[GTILE * GBK];

    const int tid  = threadIdx.x;
    const int lane = tid & 63;
    const int wave = tid >> 6;
    const int quad = lane >> 4;
    const int l16  = lane & 15;

    const int bm = blockIdx.y * GTILE;
    const int bn = blockIdx.x * GTILE;

    const int wm = (wave >> 1) * 64;   // wave quadrant within tile
    const int wn = (wave & 1) * 64;

    f32x4 acc[4][4] = {};

    // staging: chunk c = tid (t=0) and tid+256 (t=1); 16B per chunk
    const int r0 = tid >> 2;              // row within 64-row half
    const int c0 = (tid & 3) * 8;         // bf16 col offset
    const unsigned short* Ag0 = A + (size_t)(bm + r0) * K + c0;
    const unsigned short* Ag1 = A + (size_t)(bm + 64 + r0) * K + c0;
    const unsigned short* Bg0 = B + (size_t)(bn + r0) * K + c0;
    const unsigned short* Bg1 = B + (size_t)(bn + 64 + r0) * K + c0;

    // wave-uniform LDS bases (elements): chunk (t*256 + wave*64 + lane)*8
    unsigned short* AsmW0 = Asm + wave * 512;
    unsigned short* AsmW1 = Asm + 2048 + wave * 512;
    unsigned short* BsmW0 = Bsm + wave * 512;
    unsigned short* BsmW1 = Bsm + 2048 + wave * 512;

    for (int kt = 0; kt < K; kt += GBK) {
        __syncthreads();   // previous iter's LDS reads done
        gl_lds16(Ag0 + kt, AsmW0);
        gl_lds16(Ag1 + kt, AsmW1);
        gl_lds16(Bg0 + kt, BsmW0);
        gl_lds16(Bg1 + kt, BsmW1);
        __syncthreads();   // staging visible (vmcnt drained by barrier)

        bf16x8 a[4], b[4];
#pragma unroll
        for (int i = 0; i < 4; i++)
            a[i] = *(const bf16x8*)&Asm[(wm + i * 16 + l16) * GBK + quad * 8];
#pragma unroll
        for (int j = 0; j < 4; j++)
            b[j] = *(const bf16x8*)&Bsm[(wn + j * 16 + l16) * GBK + quad * 8];
#pragma unroll
        for (int i = 0; i < 4; i++)
#pragma unroll
            for (int j = 0; j < 4; j++)
                acc[i][j] = __builtin_amdgcn_mfma_f32_16x16x32_bf16(
                    a[i], b[j], acc[i][j], 0, 0, 0);
    }

    // epilogue: D row = quad*4 + r, col = l16
#pragma unroll
    for (int i = 0; i < 4; i++) {
#pragma unroll
        for (int j = 0; j < 4; j++) {
#pragma unroll
            for (int r = 0; r < 4; r++) {
                int row = bm + wm + i * 16 + quad * 4 + r;
                int col = bn + wn + j * 16 + l16;
                C[(size_t)row * N + col] = acc[i][j][r];
            }
        }
    }
}

// -------------------- elementwise: gates + conv taps + scatter -------------
__global__ void elemwise(const float* __restrict__ proj,      // [B, 3H]
                         const float* __restrict__ cs_in,     // [P, H, 3]
                         const int* __restrict__ idx,         // [B]
                         const float* __restrict__ conv_w,    // [H, 4]
                         float* __restrict__ cs_out,          // [P, H, 3]
                         unsigned short* __restrict__ g_bf,   // [B, H] bf16
                         int B, int H, int hshift, int hmask)
{
    int t = blockIdx.x * blockDim.x + threadIdx.x;
    if (t >= B * H) return;
    int b = t >> hshift;
    int h = t & hmask;
    int slot = idx[b];
    size_t prow = (size_t)b * 3 * H;
    float Bg = proj[prow + h];
    float Cg = proj[prow + H + h];
    float xv = proj[prow + 2 * H + h];
    float bx = Bg * xv;
    const float* cs = cs_in + ((size_t)slot * H + h) * 3;
    float c0 = cs[0], c1 = cs[1], c2 = cs[2];
    float4 cw = *(const float4*)(conv_w + 4 * h);
    float co = c0 * cw.x + c1 * cw.y + c2 * cw.z + bx * cw.w;
    float* os = cs_out + ((size_t)slot * H + h) * 3;
    os[0] = c1; os[1] = c2; os[2] = bx;
    g_bf[t] = f2bf(Cg * co);
}

// ---------------------------------------------------------------------------
extern "C" void kernel_launch(void* const* d_in, const int* in_sizes, int n_in,
                              void* d_out, int out_size, void* d_ws, size_t ws_size,
                              hipStream_t stream) {
    const float* hs         = (const float*)d_in[0];
    const float* conv_state = (const float*)d_in[1];
    const int*   idx        = (const int*)d_in[2];
    const float* w_in       = (const float*)d_in[3];
    const float* w_out      = (const float*)d_in[4];
    const float* conv_w     = (const float*)d_in[5];

    const int B  = in_sizes[2];                       // 2048
    const int H  = in_sizes[0] / B;                   // 2048
    const int Kc = in_sizes[5] / H;                   // 4
    const int Lc = Kc - 1;                            // 3
    const long long P = (long long)in_sizes[1] / ((long long)H * Lc);  // 8192

    float* y_out     = (float*)d_out;                 // [B, H]
    float* state_out = y_out + (size_t)B * H;         // [P, H, 3]

    // workspace layout
    unsigned short* hs_bf    = (unsigned short*)d_ws;              // B*H
    unsigned short* w_in_bf  = hs_bf + (size_t)B * H;              // 3H*H
    unsigned short* w_out_bf = w_in_bf + (size_t)3 * H * H;        // H*H
    float*          proj     = (float*)(w_out_bf + (size_t)H * H); // B*3H
    unsigned short* g_bf     = (unsigned short*)(proj + (size_t)B * 3 * H); // B*H

    const int thr = 256;

    // 1) bulk state copy (updated rows overwritten later)
    hipMemcpyAsync(state_out, conv_state, (size_t)P * H * Lc * sizeof(float),
                   hipMemcpyDeviceToDevice, stream);

    // 2) f32 -> bf16 conversions
    {
        int n4 = B * H / 4;
        cvt_f32_bf16<<<(n4 + thr - 1) / thr, thr, 0, stream>>>(
            (const float4*)hs, (ushort4*)hs_bf, n4);
    }
    {
        int n4 = 3 * H * H / 4;
        cvt_f32_bf16<<<(n4 + thr - 1) / thr, thr, 0, stream>>>(
            (const float4*)w_in, (ushort4*)w_in_bf, n4);
    }
    {
        int n4 = H * H / 4;
        cvt_f32_bf16<<<(n4 + thr - 1) / thr, thr, 0, stream>>>(
            (const float4*)w_out, (ushort4*)w_out_bf, n4);
    }

    // 3) GEMM1: proj[B, 3H] = hs_bf16 @ w_in_bf16^T
    {
        dim3 grid(3 * H / GTILE, B / GTILE);
        gemm_bt<<<grid, 256, 0, stream>>>(hs_bf, w_in_bf, proj, B, 3 * H, H);
    }

    // 4) elementwise + state scatter + g (bf16)
    {
        int hshift = 0; while ((1 << hshift) < H) hshift++;
        int n = B * H;
        elemwise<<<(n + thr - 1) / thr, thr, 0, stream>>>(
            proj, conv_state, idx, conv_w, state_out, g_bf, B, H, hshift, H - 1);
    }

    // 5) GEMM2: y[B, H] = g_bf16 @ w_out_bf16^T
    {
        dim3 grid(H / GTILE, B / GTILE);
        gemm_bt<<<grid, 256, 0, stream>>>(g_bf, w_out_bf, y_out, B, H, H);
    }
}

// Round 2
// 534.827 us; speedup vs baseline: 1.0344x; 1.0344x over previous
//
#include <hip/hip_runtime.h>
#include <hip/hip_bf16.h>

// ---------------------------------------------------------------------------
// Lfm2ShortConv decode step (B=2048, H=2048, K=4, P=8192, f32 in/out):
//   proj = hs @ w_in.T ; Bg,Cg,x = split(proj)
//   bx = Bg*x ; conv_out = [state | bx] . conv_w ; y = (Cg*conv_out) @ w_out.T
//   new_state = scatter(state, idx, [state[...,1:], bx])
// R1 changes: replace hipMemcpyAsync (suspected SDMA, slow in graphs) with a
// fused inverse-map writeback kernel; bf16 proj; split-K=2 for GEMM2.
// ---------------------------------------------------------------------------

typedef __bf16 bf16x8 __attribute__((ext_vector_type(8)));
typedef float f32x4 __attribute__((ext_vector_type(4)));

__device__ __forceinline__ unsigned short f2bf(float f) {
    union { float f; unsigned int u; } c; c.f = f;
    unsigned int u = c.u;
    u = u + 0x7FFFu + ((u >> 16) & 1u);   // RNE
    return (unsigned short)(u >> 16);
}
__device__ __forceinline__ float bf2f(unsigned short u) {
    union { unsigned int i; float f; } c; c.i = ((unsigned int)u) << 16;
    return c.f;
}

// ---- prep: all three f32->bf16 converts in one launch + inv-map init ------
__global__ void prep(const float4* __restrict__ hs, const float4* __restrict__ wi,
                     const float4* __restrict__ wo,
                     ushort4* __restrict__ hs_bf, ushort4* __restrict__ wi_bf,
                     ushort4* __restrict__ wo_bf,
                     int* __restrict__ inv, int P,
                     int n1, int n2, int n3) {
    int i = blockIdx.x * blockDim.x + threadIdx.x;
    if (i < P) inv[i] = -1;
    const float4* s; ushort4* d; int j = i;
    if (j < n1)            { s = hs; d = hs_bf; }
    else if ((j -= n1) < n2) { s = wi; d = wi_bf; }
    else if ((j -= n2) < n3) { s = wo; d = wo_bf; }
    else return;
    float4 v = s[j];
    ushort4 o; o.x = f2bf(v.x); o.y = f2bf(v.y); o.z = f2bf(v.z); o.w = f2bf(v.w);
    d[j] = o;
}

__global__ void scatter_inv(const int* __restrict__ idx, int* __restrict__ inv, int B) {
    int b = blockIdx.x * blockDim.x + threadIdx.x;
    if (b < B) inv[idx[b]] = b;
}

// -------------------- bf16 GEMM: C[M,N] = A[M,K] * B[N,K]^T ----------------
// 128x128 tile, BK=32, 4 waves, 4x4 16x16x32 MFMA tiles per wave.
// Optional split-K via blockIdx.z (f32 partials), optional bf16 output.

#define GTILE 128
#define GBK 32

__device__ __forceinline__ void gl_lds16(const unsigned short* g, unsigned short* l) {
    __builtin_amdgcn_global_load_lds(
        (const __attribute__((address_space(1))) unsigned int*)g,
        (__attribute__((address_space(3))) unsigned int*)l,
        16, 0, 0);
}

template<int OUTBF16>
__global__ __launch_bounds__(256) void gemm_bt(
    const unsigned short* __restrict__ A,  // [M,K] bf16 bits
    const unsigned short* __restrict__ B,  // [N,K] bf16 bits
    void* __restrict__ Cv,                 // [Z][M,N] f32 partials or [M,N] bf16
    int M, int N, int K, int ksplit)
{
    __shared__ __align__(16) unsigned short Asm[GTILE * GBK];
    __shared__ __align__(16) unsigned short Bsm[GTILE * GBK];

    const int tid  = threadIdx.x;
    const int lane = tid & 63;
    const int wave = tid >> 6;
    const int quad = lane >> 4;
    const int l16  = lane & 15;

    const int bm = blockIdx.y * GTILE;
    const int bn = blockIdx.x * GTILE;
    const int kb = blockIdx.z * ksplit;

    const int wm = (wave >> 1) * 64;
    const int wn = (wave & 1) * 64;

    f32x4 acc[4][4] = {};

    const int r0 = tid >> 2;
    const int c0 = (tid & 3) * 8;
    const unsigned short* Ag0 = A + (size_t)(bm + r0) * K + c0;
    const unsigned short* Ag1 = A + (size_t)(bm + 64 + r0) * K + c0;
    const unsigned short* Bg0 = B + (size_t)(bn + r0) * K + c0;
    const unsigned short* Bg1 = B + (size_t)(bn + 64 + r0) * K + c0;

    unsigned short* AsmW0 = Asm + wave * 512;
    unsigned short* AsmW1 = Asm + 2048 + wave * 512;
    unsigned short* BsmW0 = Bsm + wave * 512;
    unsigned short* BsmW1 = Bsm + 2048 + wave * 512;

    for (int kt = kb; kt < kb + ksplit; kt += GBK) {
        __syncthreads();
        gl_lds16(Ag0 + kt, AsmW0);
        gl_lds16(Ag1 + kt, AsmW1);
        gl_lds16(Bg0 + kt, BsmW0);
        gl_lds16(Bg1 + kt, BsmW1);
        __syncthreads();

        bf16x8 a[4], b[4];
#pragma unroll
        for (int i = 0; i < 4; i++)
            a[i] = *(const bf16x8*)&Asm[(wm + i * 16 + l16) * GBK + quad * 8];
#pragma unroll
        for (int j = 0; j < 4; j++)
            b[j] = *(const bf16x8*)&Bsm[(wn + j * 16 + l16) * GBK + quad * 8];
#pragma unroll
        for (int i = 0; i < 4; i++)
#pragma unroll
            for (int j = 0; j < 4; j++)
                acc[i][j] = __builtin_amdgcn_mfma_f32_16x16x32_bf16(
                    a[i], b[j], acc[i][j], 0, 0, 0);
    }

#pragma unroll
    for (int i = 0; i < 4; i++) {
#pragma unroll
        for (int j = 0; j < 4; j++) {
#pragma unroll
            for (int r = 0; r < 4; r++) {
                int row = bm + wm + i * 16 + quad * 4 + r;
                int col = bn + wn + j * 16 + l16;
                if (OUTBF16) {
                    ((unsigned short*)Cv)[(size_t)row * N + col] = f2bf(acc[i][j][r]);
                } else {
                    float* Cp = (float*)Cv + (size_t)blockIdx.z * M * N;
                    Cp[(size_t)row * N + col] = acc[i][j][r];
                }
            }
        }
    }
}

// -------- elemwise: gates (bf16 proj) + conv taps -> bx (f32), g (bf16) ----
__global__ void elemwise(const unsigned short* __restrict__ proj,  // [B,3H] bf16
                         const float* __restrict__ cs_in,          // [P,H,3]
                         const int* __restrict__ idx,              // [B]
                         const float* __restrict__ conv_w,         // [H,4]
                         float* __restrict__ bx_out,               // [B,H] f32
                         unsigned short* __restrict__ g_bf,        // [B,H] bf16
                         int B, int H, int hshift, int hmask)
{
    int t = blockIdx.x * blockDim.x + threadIdx.x;
    if (t >= B * H) return;
    int b = t >> hshift;
    int h = t & hmask;
    int slot = idx[b];
    size_t prow = (size_t)b * 3 * H;
    float Bg = bf2f(proj[prow + h]);
    float Cg = bf2f(proj[prow + H + h]);
    float xv = bf2f(proj[prow + 2 * H + h]);
    float bx = Bg * xv;
    const float* cs = cs_in + ((size_t)slot * H + h) * 3;
    float c0 = cs[0], c1 = cs[1], c2 = cs[2];
    float4 cw = *(const float4*)(conv_w + 4 * h);
    float co = c0 * cw.x + c1 * cw.y + c2 * cw.z + bx * cw.w;
    bx_out[t] = bx;
    g_bf[t] = f2bf(Cg * co);
}

// -------- writeback: full-pool state output (copy or shifted window) -------
__global__ __launch_bounds__(256) void writeback(
    const float* __restrict__ cs_in,   // [P,H,3]
    const float* __restrict__ bx,      // [B,H]
    const int* __restrict__ inv,       // [P]
    float* __restrict__ cs_out,        // [P,H,3]
    int HL, int H)                     // HL = 3*H
{
    int p = blockIdx.x;
    const float* src = cs_in + (size_t)p * HL;
    float* dst = cs_out + (size_t)p * HL;
    int b = inv[p];
    int n4 = HL / 4;
    if (b < 0) {
        const float4* s4 = (const float4*)src;
        float4* d4 = (float4*)dst;
        for (int f = threadIdx.x; f < n4; f += blockDim.x) d4[f] = s4[f];
    } else {
        const float* bxr = bx + (size_t)b * H;
        for (int f = threadIdx.x; f < n4; f += blockDim.x) {
            int e0 = 4 * f;
            float4 o;
#pragma unroll
            for (int j = 0; j < 4; j++) {
                int e = e0 + j;
                int q = e / 3, m = e - q * 3;
                ((float*)&o)[j] = (m == 2) ? bxr[q] : src[e + 1];
            }
            ((float4*)dst)[f] = o;
        }
    }
}

// -------- reduce: y = partial0 + partial1 ----------------------------------
__global__ void reduce2(const float4* __restrict__ p0, const float4* __restrict__ p1,
                        float4* __restrict__ y, int n4) {
    int i = blockIdx.x * blockDim.x + threadIdx.x;
    if (i >= n4) return;
    float4 a = p0[i], b = p1[i];
    float4 o; o.x = a.x + b.x; o.y = a.y + b.y; o.z = a.z + b.z; o.w = a.w + b.w;
    y[i] = o;
}

// ---------------------------------------------------------------------------
extern "C" void kernel_launch(void* const* d_in, const int* in_sizes, int n_in,
                              void* d_out, int out_size, void* d_ws, size_t ws_size,
                              hipStream_t stream) {
    const float* hs         = (const float*)d_in[0];
    const float* conv_state = (const float*)d_in[1];
    const int*   idx        = (const int*)d_in[2];
    const float* w_in       = (const float*)d_in[3];
    const float* w_out      = (const float*)d_in[4];
    const float* conv_w     = (const float*)d_in[5];

    const int B  = in_sizes[2];                       // 2048
    const int H  = in_sizes[0] / B;                   // 2048
    const int Kc = in_sizes[5] / H;                   // 4
    const int Lc = Kc - 1;                            // 3
    const int P  = (int)((long long)in_sizes[1] / ((long long)H * Lc)); // 8192

    float* y_out     = (float*)d_out;                 // [B,H]
    float* state_out = y_out + (size_t)B * H;         // [P,H,3]

    // workspace layout
    unsigned short* hs_bf    = (unsigned short*)d_ws;                    // B*H
    unsigned short* w_in_bf  = hs_bf + (size_t)B * H;                    // 3H*H
    unsigned short* w_out_bf = w_in_bf + (size_t)3 * H * H;              // H*H
    unsigned short* proj_bf  = w_out_bf + (size_t)H * H;                 // B*3H
    unsigned short* g_bf     = proj_bf + (size_t)B * 3 * H;              // B*H
    float*          bx       = (float*)(g_bf + (size_t)B * H);           // B*H
    float*          part     = bx + (size_t)B * H;                       // 2*B*H
    int*            inv      = (int*)(part + (size_t)2 * B * H);         // P

    const int thr = 256;

    // 1) converts + inv init (one launch)
    {
        int n1 = B * H / 4, n2 = 3 * H * H / 4, n3 = H * H / 4;
        int tot = n1 + n2 + n3;
        prep<<<(tot + thr - 1) / thr, thr, 0, stream>>>(
            (const float4*)hs, (const float4*)w_in, (const float4*)w_out,
            (ushort4*)hs_bf, (ushort4*)w_in_bf, (ushort4*)w_out_bf,
            inv, P, n1, n2, n3);
    }
    scatter_inv<<<(B + thr - 1) / thr, thr, 0, stream>>>(idx, inv, B);

    // 2) GEMM1: proj_bf[B,3H] = hs @ w_in^T (bf16 out)
    {
        dim3 grid(3 * H / GTILE, B / GTILE, 1);
        gemm_bt<1><<<grid, 256, 0, stream>>>(hs_bf, w_in_bf, proj_bf, B, 3 * H, H, H);
    }

    // 3) elemwise: bx + g
    {
        int hshift = 0; while ((1 << hshift) < H) hshift++;
        int n = B * H;
        elemwise<<<(n + thr - 1) / thr, thr, 0, stream>>>(
            proj_bf, conv_state, idx, conv_w, bx, g_bf, B, H, hshift, H - 1);
    }

    // 4) state writeback (replaces memcpy + scatter)
    writeback<<<P, 256, 0, stream>>>(conv_state, bx, inv, state_out, 3 * H, H);

    // 5) GEMM2 split-K=2: partials, then reduce into y
    {
        dim3 grid(H / GTILE, B / GTILE, 2);
        gemm_bt<0><<<grid, 256, 0, stream>>>(g_bf, w_out_bf, part, B, H, H, H / 2);
        int n4 = B * H / 4;
        reduce2<<<(n4 + thr - 1) / thr, thr, 0, stream>>>(
            (const float4*)part, (const float4*)(part + (size_t)B * H),
            (float4*)y_out, n4);
    }
}